// Round 11
// baseline (599.294 us; speedup 1.0000x reference)
//
#include <hip/hip_runtime.h>

// SJLT projection: out[b, idx[d,j]] += x[b,d] * sign(d,j), * 1/sqrt(4)
// B=64, D=524288, P=8192, C=4.
//
// Measured walls (R1-R10):
//  - LDS atomics ~3.16 cyc/lane (pipe-serialized).
//  - Global atomics ~40ns + 64B HBM write-through each.
//  - Random small global stores: 64B HBM write each.
//  - LDS += with unprovable aliasing: chained ds_read->ds_write ~130cyc/entry
//    (R10 k4: 232us invariant to occupancy & load batching).
// R11: p-major entries + wave-per-p REGISTER accumulation (zero DS in hot
// loop). Pipeline: k1b q-bucket (block-major) -> k2 qtot scan -> k3 per-q
// p-sort (LDS bins, exact CSR, coalesced 8MB write) -> k1a transpose ->
// k4 register gather (16-deep batched ushort loads, 1 fmac/entry).
//
// ws layout (need 75,532,292 <= 75,563,008 proven in R4):
//   entries16 u16[2M]      @ 0           (k1b out; dead after k3; xT overwrites)
//   lbase16  u16[1024*257] @ 4,194,304   (dead after k3)
//   xT bf16[D][64]         @ 0..67,108,864  (k1a, runs AFTER k3)
//   entries_p u32[2M]      @ 67,108,864
//   pofs u32[8192]         @ 75,497,472   (off | n<<22)
//   qtot u32[256]          @ 75,530,240
//   qbase u32[257]         @ 75,531,264

constexpr int DIM   = 524288;
constexpr int PROJ  = 8192;
constexpr int NBLK  = 1024;         // d-chunks
constexpr int DPB   = DIM / NBLK;   // 512
constexpr int NBUCK = 256;          // buckets of 32 p's
constexpr int MAXQ  = 9216;         // LDS staging cap (mean 8192 + 11 sigma)

__device__ __forceinline__ uint32_t f2bf(float f) {   // RNE f32 -> bf16 bits
    uint32_t u = __float_as_uint(f);
    return (u + 0x7fffu + ((u >> 16) & 1u)) >> 16;
}

// -------- k1a: transpose x -> xT bf16 (*0.5), packed 2 b / u32
__global__ __launch_bounds__(256) void k1a_transpose(
    const float* __restrict__ x, uint32_t* __restrict__ xT32)
{
    __shared__ float tile[64][65];
    const int d0 = blockIdx.x * 64;
    const int t  = threadIdx.x;
#pragma unroll
    for (int i = 0; i < 16; ++i) {
        const int fid = i * 256 + t;
        tile[fid >> 6][fid & 63] =
            x[(size_t)(fid >> 6) * DIM + d0 + (fid & 63)] * 0.5f;
    }
    __syncthreads();
#pragma unroll
    for (int i = 0; i < 8; ++i) {
        const int fid = i * 256 + t;
        const int dl = fid >> 5, k = fid & 31;
        xT32[(size_t)(d0 + dl) * 32 + k] =
            f2bf(tile[2 * k][dl]) | (f2bf(tile[2 * k + 1][dl]) << 16);
    }
}

// -------- k1b: q-bucketed entries (block-major) + lbase + qtot
// entry u16 = dloc<<6 | sign<<5 | ploc
__global__ __launch_bounds__(256) void k1b_entries(
    const int4* __restrict__ idx4, const int4* __restrict__ sgn4,
    uint32_t* __restrict__ entries32, uint16_t* __restrict__ lbase16,
    uint32_t* __restrict__ qtot)
{
    __shared__ uint32_t lcnt[NBUCK];
    __shared__ uint32_t lb[NBUCK + 1];
    __shared__ uint32_t cur[NBUCK];
    __shared__ uint16_t staged[2048];
    const int t    = threadIdx.x;
    const int blk  = blockIdx.x;
    const int dblk = blk * DPB;

    lcnt[t] = 0;
    __syncthreads();

    const int4 ia = idx4[dblk + 2 * t];
    const int4 ib = idx4[dblk + 2 * t + 1];
    const int4 sa = sgn4[dblk + 2 * t];
    const int4 sb = sgn4[dblk + 2 * t + 1];

    atomicAdd(&lcnt[ia.x >> 5], 1u);
    atomicAdd(&lcnt[ia.y >> 5], 1u);
    atomicAdd(&lcnt[ia.z >> 5], 1u);
    atomicAdd(&lcnt[ia.w >> 5], 1u);
    atomicAdd(&lcnt[ib.x >> 5], 1u);
    atomicAdd(&lcnt[ib.y >> 5], 1u);
    atomicAdd(&lcnt[ib.z >> 5], 1u);
    atomicAdd(&lcnt[ib.w >> 5], 1u);
    __syncthreads();

    atomicAdd(&qtot[t], lcnt[t]);               // global bucket totals

    if (t < 64) {                               // wave-0 exclusive scan
        uint32_t c4[4], s = 0;
#pragma unroll
        for (int i = 0; i < 4; ++i) { c4[i] = lcnt[t * 4 + i]; s += c4[i]; }
        uint32_t v = s;
#pragma unroll
        for (int off = 1; off < 64; off <<= 1) {
            uint32_t u = __shfl_up(v, off);
            if (t >= off) v += u;
        }
        uint32_t base = v - s;
#pragma unroll
        for (int i = 0; i < 4; ++i) { lb[t * 4 + i] = base; base += c4[i]; }
        if (t == 63) lb[256] = base;            // 2048
    }
    __syncthreads();
    cur[t] = lb[t];
    __syncthreads();

    auto stage = [&](int p, int s, uint32_t dsh) {
        uint32_t pos = atomicAdd(&cur[(uint32_t)p >> 5], 1u);
        staged[pos] = (uint16_t)(dsh | ((uint32_t)(s & 1) << 5) | ((uint32_t)p & 31u));
    };
    const uint32_t dA = (uint32_t)(2 * t)     << 6;
    const uint32_t dB = (uint32_t)(2 * t + 1) << 6;
    stage(ia.x, sa.x, dA); stage(ia.y, sa.y, dA);
    stage(ia.z, sa.z, dA); stage(ia.w, sa.w, dA);
    stage(ib.x, sb.x, dB); stage(ib.y, sb.y, dB);
    stage(ib.z, sb.z, dB); stage(ib.w, sb.w, dB);
    __syncthreads();

    const uint32_t* st32 = (const uint32_t*)staged;
    for (int i = t; i < 1024; i += 256)
        entries32[(size_t)blk * 1024 + i] = st32[i];
    lbase16[(size_t)blk * 257 + t] = (uint16_t)lb[t];
    if (t == 0) lbase16[(size_t)blk * 257 + 256] = (uint16_t)lb[256];
}

// -------- k2: exclusive scan of qtot -> qbase
__global__ __launch_bounds__(256) void k2_qscan(
    const uint32_t* __restrict__ qtot, uint32_t* __restrict__ qbase)
{
    __shared__ uint32_t wsum[4];
    const int t = threadIdx.x, lane = t & 63;
    uint32_t v = qtot[t];
    uint32_t x = v;
#pragma unroll
    for (int off = 1; off < 64; off <<= 1) {
        uint32_t u = __shfl_up(x, off);
        if (lane >= off) x += u;
    }
    if (lane == 63) wsum[t >> 6] = x;
    __syncthreads();
    uint32_t wb = 0;
    for (int i = 0; i < (t >> 6); ++i) wb += wsum[i];
    qbase[t] = wb + x - v;
    if (t == 255) qbase[256] = wb + x;
}

// -------- k3: per-q p-sort into exact CSR (block = bucket q)
// entries_p value = d<<7 | sign  (row byte offset = e & ~127)
__global__ __launch_bounds__(256) void k3_sort(
    const uint16_t* __restrict__ entries16, const uint16_t* __restrict__ lbase16,
    const uint32_t* __restrict__ qbase, uint32_t* __restrict__ entries_p,
    uint32_t* __restrict__ pofs)
{
    __shared__ uint32_t staged[MAXQ];            // 36 KB
    __shared__ uint32_t cnt32[32], ofs32[32], curp[32];
    const int t    = threadIdx.x;
    const int lane = t & 63;
    const int w    = t >> 6;                     // 4 waves, 256 blks each
    const int q    = blockIdx.x;

    if (t < 32) cnt32[t] = 0;
    __syncthreads();

    for (int blk = w * 256; blk < w * 256 + 256; ++blk) {   // pass A: count
        const uint32_t s = lbase16[(size_t)blk * 257 + q];
        const uint32_t e = lbase16[(size_t)blk * 257 + q + 1];
        const uint32_t i = s + (uint32_t)lane;
        if (i < e) {
            const uint32_t e16 = entries16[(size_t)blk * 2048 + i];
            atomicAdd(&cnt32[e16 & 31u], 1u);
        }
    }
    __syncthreads();
    if (t < 32) {                                // scan 32 p-counts
        uint32_t v = cnt32[t];
        uint32_t x = v;
#pragma unroll
        for (int off = 1; off < 32; off <<= 1) {
            uint32_t u = __shfl_up(x, off);
            if (t >= off) x += u;
        }
        ofs32[t] = x - v;
        curp[t]  = x - v;
    }
    __syncthreads();

    for (int blk = w * 256; blk < w * 256 + 256; ++blk) {   // pass B: place
        const uint32_t s = lbase16[(size_t)blk * 257 + q];
        const uint32_t e = lbase16[(size_t)blk * 257 + q + 1];
        const uint32_t i = s + (uint32_t)lane;
        if (i < e) {
            const uint32_t e16 = entries16[(size_t)blk * 2048 + i];
            const uint32_t pos = atomicAdd(&curp[e16 & 31u], 1u);
            if (pos < (uint32_t)MAXQ) {
                const uint32_t d = ((uint32_t)blk << 9) + (e16 >> 6);
                staged[pos] = (d << 7) | ((e16 >> 5) & 1u);
            }
        }
    }
    __syncthreads();

    const uint32_t qb  = qbase[q];
    const uint32_t tot = qbase[q + 1] - qb;
    for (uint32_t i = t; i < tot; i += 256)      // coalesced exact-CSR write
        entries_p[qb + i] = staged[i];
    if (t < 32)
        pofs[q * 32 + t] = (qb + ofs32[t]) | (cnt32[t] << 22);
}

// -------- k4: wave-per-p register gather. 1024 blocks x 8 waves.
__global__ __launch_bounds__(512) void k4_reg(
    const uint32_t* __restrict__ entries_p, const uint32_t* __restrict__ pofs,
    const uint16_t* __restrict__ xT16, float* __restrict__ out)
{
    const int t    = threadIdx.x;
    const int lane = t & 63;                     // lane = batch b
    const int w    = t >> 6;
    const int p    = blockIdx.x * 8 + w;
    const uint32_t packed = pofs[p];             // wave-uniform
    const uint32_t off = packed & 0x3fffffu;
    const uint32_t n   = packed >> 22;

    float acc = 0.f;
    uint32_t gi = 0;
    while (gi < n) {
        uint32_t li  = off + gi + (uint32_t)lane;
        const uint32_t lim = off + n - 1u;
        if (li > lim) li = lim;
        const uint32_t ev = entries_p[li];       // 64-entry chunk, coalesced
        uint32_t m = n - gi; if (m > 64u) m = 64u;
        uint32_t done = 0;
        while (done < m) {
            uint32_t cntE = m - done; if (cntE > 16u) cntE = 16u;
            uint32_t us[16];
            float    sg[16];
#pragma unroll
            for (int j = 0; j < 16; ++j) {       // phase A: 16 loads in flight
                if ((uint32_t)j < cntE) {
                    const uint32_t e = __builtin_amdgcn_readlane(ev, (int)done + j);
                    sg[j] = (e & 1u) ? 1.0f : -1.0f;          // scalar
                    us[j] = (uint32_t)xT16[(size_t)(e >> 7) * 64 + lane];
                }
            }
#pragma unroll
            for (int j = 0; j < 16; ++j) {       // phase B: 1 fmac each
                if ((uint32_t)j < cntE)
                    acc = fmaf(sg[j], __uint_as_float(us[j] << 16), acc);
            }
            done += cntE;
        }
        gi += m;
    }
    out[(size_t)lane * PROJ + p] = acc;          // full coverage, no memset
}

// ------------------------------------------------- fallback (R3 scatter)
__device__ __forceinline__ void lds_fadd(uint32_t byte_addr, float v) {
    asm volatile("ds_add_f32 %0, %1" :: "v"(byte_addr), "v"(v) : "memory");
}
__device__ __forceinline__ void lds_fadd_off32k(uint32_t byte_addr, float v) {
    asm volatile("ds_add_f32 %0, %1 offset:32768" :: "v"(byte_addr), "v"(v) : "memory");
}

__global__ __launch_bounds__(1024) void sjlt_scatter(
    const float* __restrict__ x, const int4* __restrict__ idx4,
    const int4* __restrict__ sgn4, float* __restrict__ out)
{
    __shared__ float acc[4 * PROJ];
    for (int i = threadIdx.x; i < 4 * PROJ; i += 1024) acc[i] = 0.0f;
    __syncthreads();
    const int row0 = blockIdx.y * 4;
    const int dbeg = blockIdx.x * (DIM / 16);
    const uint32_t accBase = (uint32_t)(uintptr_t)(&acc[0]);
    const float* xr0 = x + (size_t)(row0 + 0) * DIM;
    const float* xr1 = x + (size_t)(row0 + 1) * DIM;
    const float* xr2 = x + (size_t)(row0 + 2) * DIM;
    const float* xr3 = x + (size_t)(row0 + 3) * DIM;
    for (int d = dbeg + (int)threadIdx.x; d < dbeg + DIM / 16; d += 1024) {
        const int4 iv = idx4[d];
        const int4 sv = sgn4[d];
        const uint32_t u0 = __float_as_uint(xr0[d]);
        const uint32_t u1 = __float_as_uint(xr1[d]);
        const uint32_t u2 = __float_as_uint(xr2[d]);
        const uint32_t u3 = __float_as_uint(xr3[d]);
        const int p[4] = {iv.x, iv.y, iv.z, iv.w};
        const int s[4] = {sv.x, sv.y, sv.z, sv.w};
#pragma unroll
        for (int j = 0; j < 4; ++j) {
            const uint32_t flip = (uint32_t)(s[j] ^ 1) << 31;
            const uint32_t a01  = accBase + ((uint32_t)p[j] << 2);
            const uint32_t a23  = a01 + 2u * 32768u;
            lds_fadd        (a01, __uint_as_float(u0 ^ flip));
            lds_fadd_off32k (a01, __uint_as_float(u1 ^ flip));
            lds_fadd        (a23, __uint_as_float(u2 ^ flip));
            lds_fadd_off32k (a23, __uint_as_float(u3 ^ flip));
        }
    }
    __syncthreads();
    for (int i = threadIdx.x; i < 4 * PROJ; i += 1024) {
        const int r  = i >> 13;
        const int pp = i & (PROJ - 1);
        unsafeAtomicAdd(&out[(size_t)(row0 + r) * PROJ + pp], acc[i] * 0.5f);
    }
}

// --------------------------------------------------------------- launch
extern "C" void kernel_launch(void* const* d_in, const int* in_sizes, int n_in,
                              void* d_out, int out_size, void* d_ws, size_t ws_size,
                              hipStream_t stream) {
    const float* x   = (const float*)d_in[0];
    const int4*  idx = (const int4*) d_in[1];
    const int4*  sgn = (const int4*) d_in[2];
    float*       out = (float*)d_out;

    const size_t need = 75532292;
    if (ws_size >= need) {
        uint8_t*  ws        = (uint8_t*)d_ws;
        uint32_t* entries32 = (uint32_t*)ws;                 // aka entries16
        uint16_t* entries16 = (uint16_t*)ws;
        uint16_t* lbase16   = (uint16_t*)(ws +  4194304);
        uint32_t* xT32      = (uint32_t*)ws;                 // after k3
        uint16_t* xT16      = (uint16_t*)ws;
        uint32_t* entries_p = (uint32_t*)(ws + 67108864);
        uint32_t* pofs      = (uint32_t*)(ws + 75497472);
        uint32_t* qtot      = (uint32_t*)(ws + 75530240);
        uint32_t* qbase     = (uint32_t*)(ws + 75531264);

        hipMemsetAsync(qtot, 0, NBUCK * sizeof(uint32_t), stream);
        k1b_entries  <<<NBLK,     256, 0, stream>>>(idx, sgn, entries32, lbase16, qtot);
        k2_qscan     <<<1,        256, 0, stream>>>(qtot, qbase);
        k3_sort      <<<NBUCK,    256, 0, stream>>>(entries16, lbase16, qbase, entries_p, pofs);
        k1a_transpose<<<DIM / 64, 256, 0, stream>>>(x, xT32);   // clobbers entries16/lbase16
        k4_reg       <<<PROJ / 8, 512, 0, stream>>>(entries_p, pofs, xT16, out);
    } else {
        // ws too small: R3 LDS-scatter path (passes at ~830 us)
        hipMemsetAsync(d_out, 0, (size_t)out_size * sizeof(float), stream);
        dim3 grid(16, 16);
        sjlt_scatter<<<grid, 1024, 0, stream>>>(x, idx, sgn, out);
    }
}